// Round 7
// baseline (61.668 us; speedup 1.0000x reference)
//
#include <hip/hip_runtime.h>
#include <stdint.h>

namespace {

constexpr int kB = 8;
constexpr int kV = 5023;
constexpr int kF = 9976;
constexpr int kH = 512;
constexpr int kW = 512;
constexpr int kL = 5;
constexpr int kHW = kH * kW;
constexpr int kQ = kHW / 4;   // pixel quads per batch
constexpr int kQH = kQ / 2;   // half-range of quads (each thread does 2 quads)
constexpr int kCap = 32;      // max faces per vertex (lambda ~ 6)

typedef float nfloat4 __attribute__((ext_vector_type(4)));
typedef int nint4 __attribute__((ext_vector_type(4)));

__device__ __forceinline__ float h2f(uint32_t u) {
  _Float16 h;
  uint16_t s = (uint16_t)u;
  __builtin_memcpy(&h, &s, 2);
  return (float)h;
}
__device__ __forceinline__ uint32_t f2h(float f) {
  _Float16 h = (_Float16)f;
  uint16_t s;
  __builtin_memcpy(&s, &h, 2);
  return (uint32_t)s;
}

__device__ __forceinline__ void cross3(float ax, float ay, float az,
                                       float bx, float by, float bz,
                                       float& cx, float& cy, float& cz) {
  cx = ay * bz - az * by;
  cy = az * bx - ax * bz;
  cz = ax * by - ay * bx;
}

// Zero adjacency counters + pre-normalize lights into packed float4 pairs.
__global__ void init_kernel(int* __restrict__ cnt,
                            const float* __restrict__ lights,
                            float4* __restrict__ ldir4) {
  int idx = blockIdx.x * blockDim.x + threadIdx.x;
  for (int i = idx; i < kV; i += gridDim.x * blockDim.x) cnt[i] = 0;
  if (idx < kB * kL) {
    float dx = lights[idx * 6 + 0];
    float dy = lights[idx * 6 + 1];
    float dz = lights[idx * 6 + 2];
    float inv = 1.0f / fmaxf(sqrtf(dx * dx + dy * dy + dz * dz), 1e-12f);
    ldir4[idx * 2 + 0] = make_float4(dx * inv, dy * inv, dz * inv, 0.0f);
    ldir4[idx * 2 + 1] =
        make_float4(lights[idx * 6 + 3], lights[idx * 6 + 4], lights[idx * 6 + 5], 0.0f);
  }
}

// Fused: threads [0,kF) build vertex->face adjacency (int atomics);
// threads [kF, kF+kB*kF) compute per-(b,f) face normals for both meshes.
__global__ void prep_kernel(const float* __restrict__ verts,
                            const float* __restrict__ tverts,
                            const int* __restrict__ faces,
                            int* __restrict__ cnt,
                            int* __restrict__ adj,
                            float4* __restrict__ fn) {
  int idx = blockIdx.x * blockDim.x + threadIdx.x;
  if (idx < kF) {
    int f = idx;
#pragma unroll
    for (int c = 0; c < 3; ++c) {
      int v = faces[f * 3 + c];
      int slot = atomicAdd(&cnt[v], 1);
      if (slot < kCap) adj[v * kCap + slot] = f;
    }
    return;
  }
  idx -= kF;
  if (idx >= kB * kF) return;
  int b = idx / kF;
  int f = idx - b * kF;
  int i0 = faces[f * 3 + 0];
  int i1 = faces[f * 3 + 1];
  int i2 = faces[f * 3 + 2];

  float nx, ny, nz, tx, ty, tz;
  {
    const float* vb = verts + (size_t)b * kV * 3;
    float v0x = vb[i0 * 3 + 0], v0y = vb[i0 * 3 + 1], v0z = vb[i0 * 3 + 2];
    float v1x = vb[i1 * 3 + 0], v1y = vb[i1 * 3 + 1], v1z = vb[i1 * 3 + 2];
    float v2x = vb[i2 * 3 + 0], v2y = vb[i2 * 3 + 1], v2z = vb[i2 * 3 + 2];
    cross3(v1x - v0x, v1y - v0y, v1z - v0z, v2x - v0x, v2y - v0y, v2z - v0z,
           nx, ny, nz);
  }
  {
    const float* vb = tverts + (size_t)b * kV * 3;
    // fp-faithful to reference: add 10 to z BEFORE differencing
    float v0x = vb[i0 * 3 + 0], v0y = vb[i0 * 3 + 1], v0z = vb[i0 * 3 + 2] + 10.0f;
    float v1x = vb[i1 * 3 + 0], v1y = vb[i1 * 3 + 1], v1z = vb[i1 * 3 + 2] + 10.0f;
    float v2x = vb[i2 * 3 + 0], v2y = vb[i2 * 3 + 1], v2z = vb[i2 * 3 + 2] + 10.0f;
    cross3(v1x - v0x, v1y - v0y, v1z - v0z, v2x - v0x, v2y - v0y, v2z - v0z,
           tx, ty, tz);
  }
  fn[(size_t)idx * 2 + 0] = make_float4(nx, ny, nz, tx);
  fn[(size_t)idx * 2 + 1] = make_float4(ty, tz, 0.0f, 0.0f);
}

// Per (b,v): gather-sum adjacent face normals, normalize.
__global__ void gather_normalize_kernel(const int* __restrict__ cnt,
                                        const int* __restrict__ adj,
                                        const float4* __restrict__ fn,
                                        float* __restrict__ normals,
                                        float* __restrict__ tz) {
  int idx = blockIdx.x * blockDim.x + threadIdx.x;
  if (idx >= kB * kV) return;
  int b = idx / kV;
  int v = idx - b * kV;
  int e = min(cnt[v], kCap);
  float nx = 0.f, ny = 0.f, nz = 0.f, tx = 0.f, ty = 0.f, tzv = 0.f;
  const int* av = adj + v * kCap;
  for (int j = 0; j < e; ++j) {
    int f = av[j];
    size_t k = ((size_t)b * kF + f) * 2;
    float4 a = fn[k];
    float4 c = fn[k + 1];
    nx += a.x;
    ny += a.y;
    nz += a.z;
    tx += a.w;
    ty += c.x;
    tzv += c.y;
  }
  float inv = 1.0f / fmaxf(sqrtf(nx * nx + ny * ny + nz * nz), 1e-6f);
  normals[(size_t)idx * 3 + 0] = nx * inv;
  normals[(size_t)idx * 3 + 1] = ny * inv;
  normals[(size_t)idx * 3 + 2] = nz * inv;
  float invt = 1.0f / fmaxf(sqrtf(tx * tx + ty * ty + tzv * tzv), 1e-6f);
  tz[idx] = tzv * invt;
}

// Per (b,f): pack corners into 32B: fp16 normals + fp32 tz (mask-critical).
__global__ void faceattr_kernel(const int* __restrict__ faces,
                                const float* __restrict__ normals,
                                const float* __restrict__ tz,
                                uint4* __restrict__ fattr) {
  int idx = blockIdx.x * blockDim.x + threadIdx.x;
  if (idx >= kB * kF) return;
  int b = idx / kF;
  int f = idx - b * kF;
  int i0 = faces[f * 3 + 0];
  int i1 = faces[f * 3 + 1];
  int i2 = faces[f * 3 + 2];
  const float* nb = normals + (size_t)b * kV * 3;
  const float* tzb = tz + (size_t)b * kV;
  uint32_t h[9];
  h[0] = f2h(nb[i0 * 3 + 0]);
  h[1] = f2h(nb[i0 * 3 + 1]);
  h[2] = f2h(nb[i0 * 3 + 2]);
  h[3] = f2h(nb[i1 * 3 + 0]);
  h[4] = f2h(nb[i1 * 3 + 1]);
  h[5] = f2h(nb[i1 * 3 + 2]);
  h[6] = f2h(nb[i2 * 3 + 0]);
  h[7] = f2h(nb[i2 * 3 + 1]);
  h[8] = f2h(nb[i2 * 3 + 2]);
  uint4 w0, w1;
  w0.x = h[0] | (h[1] << 16);
  w0.y = h[2] | (h[3] << 16);
  w0.z = h[4] | (h[5] << 16);
  w0.w = h[6] | (h[7] << 16);
  w1.x = h[8];
  w1.y = __float_as_uint(tzb[i0]);
  w1.z = __float_as_uint(tzb[i1]);
  w1.w = __float_as_uint(tzb[i2]);
  fattr[(size_t)idx * 2 + 0] = w0;
  fattr[(size_t)idx * 2 + 1] = w1;
}

__device__ __forceinline__ nfloat4 nt_loadf4(const float4* p) {
  return __builtin_nontemporal_load((const nfloat4*)p);
}
__device__ __forceinline__ nint4 nt_loadi4(const int4* p) {
  return __builtin_nontemporal_load((const nint4*)p);
}

// 8 pixels per thread (2 quads from opposite half-ranges -> all streaming
// accesses stay wave-coalesced). 16 independent gathers in flight. NT loads
// on streaming inputs + NT stores on output keep L2 for fattr.
__global__ void __launch_bounds__(256) pixel8_kernel(
    const int4* __restrict__ p2f4,
    const float4* __restrict__ bary4,
    const uint4* __restrict__ fattr,
    const float4* __restrict__ ldir4,
    const float4* __restrict__ img4,
    float4* __restrict__ out4) {
  int g = blockIdx.x * blockDim.x + threadIdx.x;
  if (g >= kB * kQH) return;
  int b = g / kQH;
  int qa = g - b * kQH;        // quad A
  int qb = qa + kQH;           // quad B (other half of the batch range)
  size_t ga = (size_t)b * kQ + qa;
  size_t gb = (size_t)b * kQ + qb;

  // ---- issue ALL streaming loads + gathers up front ----
  nint4 fa4 = nt_loadi4(&p2f4[ga]);
  nint4 fb4 = nt_loadi4(&p2f4[gb]);

  nfloat4 wa0 = nt_loadf4(&bary4[ga * 3 + 0]);
  nfloat4 wa1 = nt_loadf4(&bary4[ga * 3 + 1]);
  nfloat4 wa2 = nt_loadf4(&bary4[ga * 3 + 2]);
  nfloat4 wb0 = nt_loadf4(&bary4[gb * 3 + 0]);
  nfloat4 wb1 = nt_loadf4(&bary4[gb * 3 + 1]);
  nfloat4 wb2 = nt_loadf4(&bary4[gb * 3 + 2]);

  int fi[8] = {fa4.x, fa4.y, fa4.z, fa4.w, fb4.x, fb4.y, fb4.z, fb4.w};

  uint4 A[8], T[8];
  bool valid[8];
#pragma unroll
  for (int k = 0; k < 8; ++k) {
    bool v = fi[k] < kF;
    valid[k] = v;
    int f = v ? fi[k] : (kF - 1);
    size_t base = ((size_t)b * kF + f) * 2;
    A[k] = fattr[base + 0];
    T[k] = fattr[base + 1];
  }

  size_t iba = (size_t)b * 3 * kQ + qa;
  size_t ibb = (size_t)b * 3 * kQ + qb;
  nfloat4 ia0 = nt_loadf4(&img4[iba + 0 * (size_t)kQ]);
  nfloat4 ia1 = nt_loadf4(&img4[iba + 1 * (size_t)kQ]);
  nfloat4 ia2 = nt_loadf4(&img4[iba + 2 * (size_t)kQ]);
  nfloat4 ib0 = nt_loadf4(&img4[ibb + 0 * (size_t)kQ]);
  nfloat4 ib1 = nt_loadf4(&img4[ibb + 1 * (size_t)kQ]);
  nfloat4 ib2 = nt_loadf4(&img4[ibb + 2 * (size_t)kQ]);

  float bw[8][3] = {{wa0.x, wa0.y, wa0.z}, {wa0.w, wa1.x, wa1.y},
                    {wa1.z, wa1.w, wa2.x}, {wa2.y, wa2.z, wa2.w},
                    {wb0.x, wb0.y, wb0.z}, {wb0.w, wb1.x, wb1.y},
                    {wb1.z, wb1.w, wb2.x}, {wb2.y, wb2.z, wb2.w}};
  float im[8][3] = {{ia0.x, ia1.x, ia2.x}, {ia0.y, ia1.y, ia2.y},
                    {ia0.z, ia1.z, ia2.z}, {ia0.w, ia1.w, ia2.w},
                    {ib0.x, ib1.x, ib2.x}, {ib0.y, ib1.y, ib2.y},
                    {ib0.z, ib1.z, ib2.z}, {ib0.w, ib1.w, ib2.w}};

  // Light data: wave-uniform b -> scalar loads.
  int bu = __builtin_amdgcn_readfirstlane(b);
  const float4* lb4 = ldir4 + (size_t)bu * kL * 2;
  float ld[kL][3], lc[kL][3];
#pragma unroll
  for (int l = 0; l < kL; ++l) {
    float4 d = lb4[l * 2 + 0];
    float4 c = lb4[l * 2 + 1];
    ld[l][0] = d.x;
    ld[l][1] = d.y;
    ld[l][2] = d.z;
    lc[l][0] = c.x;
    lc[l][1] = c.y;
    lc[l][2] = c.z;
  }

  float o[8][3];
#pragma unroll
  for (int k = 0; k < 8; ++k) {
    float b0 = bw[k][0], b1 = bw[k][1], b2 = bw[k][2];
    float inv = 1.0f / (b0 + b1 + b2);
    b0 *= inv;
    b1 *= inv;
    b2 *= inv;
    float n0x = h2f(A[k].x), n0y = h2f(A[k].x >> 16);
    float n0z = h2f(A[k].y), n1x = h2f(A[k].y >> 16);
    float n1y = h2f(A[k].z), n1z = h2f(A[k].z >> 16);
    float n2x = h2f(A[k].w), n2y = h2f(A[k].w >> 16);
    float n2z = h2f(T[k].x);
    float tz0 = __uint_as_float(T[k].y);
    float tz1 = __uint_as_float(T[k].z);
    float tz2 = __uint_as_float(T[k].w);

    float tzi = b0 * tz0 + b1 * tz1 + b2 * tz2;
    bool alpha = valid[k] && (tzi < 0.15f);
    float nx = b0 * n0x + b1 * n1x + b2 * n2x;
    float ny = b0 * n0y + b1 * n1y + b2 * n2y;
    float nz = b0 * n0z + b1 * n1z + b2 * n2z;
    float s0 = 0.f, s1 = 0.f, s2 = 0.f;
#pragma unroll
    for (int l = 0; l < kL; ++l) {
      float d = nx * ld[l][0] + ny * ld[l][1] + nz * ld[l][2];
      d = fminf(fmaxf(d, 0.0f), 1.0f);
      s0 += d * lc[l][0];
      s1 += d * lc[l][1];
      s2 += d * lc[l][2];
    }
    const float kk = (180.0f / 255.0f) / (float)kL;
    o[k][0] = alpha ? kk * s0 : im[k][0];
    o[k][1] = alpha ? kk * s1 : im[k][1];
    o[k][2] = alpha ? kk * s2 : im[k][2];
  }

#pragma unroll
  for (int c = 0; c < 3; ++c) {
    nfloat4 va = {o[0][c], o[1][c], o[2][c], o[3][c]};
    nfloat4 vb = {o[4][c], o[5][c], o[6][c], o[7][c]};
    __builtin_nontemporal_store(va, (nfloat4*)&out4[iba + c * (size_t)kQ]);
    __builtin_nontemporal_store(vb, (nfloat4*)&out4[ibb + c * (size_t)kQ]);
  }
}

}  // namespace

extern "C" void kernel_launch(void* const* d_in, const int* in_sizes, int n_in,
                              void* d_out, int out_size, void* d_ws, size_t ws_size,
                              hipStream_t stream) {
  const float* vertices = (const float*)d_in[0];
  const float* tvertices = (const float*)d_in[1];
  const float* lights = (const float*)d_in[2];
  const float* images = (const float*)d_in[3];
  const float* bary = (const float*)d_in[4];
  const int* faces = (const int*)d_in[5];
  const int* p2f = (const int*)d_in[6];
  float* out = (float*)d_out;

  // workspace layout (16B-aligned chunks)
  char* ws = (char*)d_ws;
  int* cnt = (int*)ws;                                   // kV ints
  ws += ((size_t)kV * sizeof(int) + 15) & ~15ull;
  int* adj = (int*)ws;                                   // kV*kCap ints
  ws += ((size_t)kV * kCap * sizeof(int) + 15) & ~15ull;
  float4* fn = (float4*)ws;                              // kB*kF*2 float4
  ws += (size_t)kB * kF * 2 * sizeof(float4);
  float* normals = (float*)ws;                           // kB*kV*3
  ws += ((size_t)kB * kV * 3 * sizeof(float) + 15) & ~15ull;
  float* tz = (float*)ws;                                // kB*kV
  ws += ((size_t)kB * kV * sizeof(float) + 15) & ~15ull;
  float4* ldir4 = (float4*)ws;                           // kB*kL*2 float4
  ws += (size_t)kB * kL * 2 * sizeof(float4);
  uint4* fattr = (uint4*)ws;                             // kB*kF*2 uint4

  {
    init_kernel<<<20, 256, 0, stream>>>(cnt, lights, ldir4);
  }
  {
    int n = kF + kB * kF;
    prep_kernel<<<(n + 255) / 256, 256, 0, stream>>>(vertices, tvertices, faces, cnt,
                                                     adj, fn);
  }
  {
    int n = kB * kV;
    gather_normalize_kernel<<<(n + 255) / 256, 256, 0, stream>>>(cnt, adj, fn, normals,
                                                                 tz);
  }
  {
    int n = kB * kF;
    faceattr_kernel<<<(n + 255) / 256, 256, 0, stream>>>(faces, normals, tz, fattr);
  }
  {
    int n = kB * kQH;
    pixel8_kernel<<<(n + 255) / 256, 256, 0, stream>>>((const int4*)p2f, (const float4*)bary,
                                                       fattr, ldir4, (const float4*)images,
                                                       (float4*)out);
  }
}

// Round 8
// 49.866 us; speedup vs baseline: 1.2367x; 1.2367x over previous
//
#include <hip/hip_runtime.h>
#include <stdint.h>

namespace {

constexpr int kB = 8;
constexpr int kV = 5023;
constexpr int kF = 9976;
constexpr int kH = 512;
constexpr int kW = 512;
constexpr int kL = 5;
constexpr int kHW = kH * kW;
constexpr int kQ = kHW / 4;   // pixel quads per batch
constexpr int kCap = 32;      // max faces per vertex (lambda ~ 6)

typedef float nfloat4 __attribute__((ext_vector_type(4)));

__device__ __forceinline__ float h2f(uint32_t u) {
  _Float16 h;
  uint16_t s = (uint16_t)u;
  __builtin_memcpy(&h, &s, 2);
  return (float)h;
}
__device__ __forceinline__ uint32_t f2h(float f) {
  _Float16 h = (_Float16)f;
  uint16_t s;
  __builtin_memcpy(&s, &h, 2);
  return (uint32_t)s;
}

__device__ __forceinline__ void cross3(float ax, float ay, float az,
                                       float bx, float by, float bz,
                                       float& cx, float& cy, float& cz) {
  cx = ay * bz - az * by;
  cy = az * bx - ax * bz;
  cz = ax * by - ay * bx;
}

// Zero adjacency counters + pre-normalize lights into packed float4 pairs.
__global__ void init_kernel(int* __restrict__ cnt,
                            const float* __restrict__ lights,
                            float4* __restrict__ ldir4) {
  int idx = blockIdx.x * blockDim.x + threadIdx.x;
  for (int i = idx; i < kV; i += gridDim.x * blockDim.x) cnt[i] = 0;
  if (idx < kB * kL) {
    float dx = lights[idx * 6 + 0];
    float dy = lights[idx * 6 + 1];
    float dz = lights[idx * 6 + 2];
    float inv = 1.0f / fmaxf(sqrtf(dx * dx + dy * dy + dz * dz), 1e-12f);
    ldir4[idx * 2 + 0] = make_float4(dx * inv, dy * inv, dz * inv, 0.0f);
    ldir4[idx * 2 + 1] =
        make_float4(lights[idx * 6 + 3], lights[idx * 6 + 4], lights[idx * 6 + 5], 0.0f);
  }
}

// Fused: threads [0,kF) build vertex->face adjacency (int atomics);
// threads [kF, kF+kB*kF) compute per-(b,f) face normals for both meshes.
__global__ void prep_kernel(const float* __restrict__ verts,
                            const float* __restrict__ tverts,
                            const int* __restrict__ faces,
                            int* __restrict__ cnt,
                            int* __restrict__ adj,
                            float4* __restrict__ fn) {
  int idx = blockIdx.x * blockDim.x + threadIdx.x;
  if (idx < kF) {
    int f = idx;
#pragma unroll
    for (int c = 0; c < 3; ++c) {
      int v = faces[f * 3 + c];
      int slot = atomicAdd(&cnt[v], 1);
      if (slot < kCap) adj[v * kCap + slot] = f;
    }
    return;
  }
  idx -= kF;
  if (idx >= kB * kF) return;
  int b = idx / kF;
  int f = idx - b * kF;
  int i0 = faces[f * 3 + 0];
  int i1 = faces[f * 3 + 1];
  int i2 = faces[f * 3 + 2];

  float nx, ny, nz, tx, ty, tz;
  {
    const float* vb = verts + (size_t)b * kV * 3;
    float v0x = vb[i0 * 3 + 0], v0y = vb[i0 * 3 + 1], v0z = vb[i0 * 3 + 2];
    float v1x = vb[i1 * 3 + 0], v1y = vb[i1 * 3 + 1], v1z = vb[i1 * 3 + 2];
    float v2x = vb[i2 * 3 + 0], v2y = vb[i2 * 3 + 1], v2z = vb[i2 * 3 + 2];
    cross3(v1x - v0x, v1y - v0y, v1z - v0z, v2x - v0x, v2y - v0y, v2z - v0z,
           nx, ny, nz);
  }
  {
    const float* vb = tverts + (size_t)b * kV * 3;
    // fp-faithful to reference: add 10 to z BEFORE differencing
    float v0x = vb[i0 * 3 + 0], v0y = vb[i0 * 3 + 1], v0z = vb[i0 * 3 + 2] + 10.0f;
    float v1x = vb[i1 * 3 + 0], v1y = vb[i1 * 3 + 1], v1z = vb[i1 * 3 + 2] + 10.0f;
    float v2x = vb[i2 * 3 + 0], v2y = vb[i2 * 3 + 1], v2z = vb[i2 * 3 + 2] + 10.0f;
    cross3(v1x - v0x, v1y - v0y, v1z - v0z, v2x - v0x, v2y - v0y, v2z - v0z,
           tx, ty, tz);
  }
  fn[(size_t)idx * 2 + 0] = make_float4(nx, ny, nz, tx);
  fn[(size_t)idx * 2 + 1] = make_float4(ty, tz, 0.0f, 0.0f);
}

// Per (b,v): gather-sum adjacent face normals, normalize, write packed
// 16B vertex record {n fp16 x3, tz fp32}.
__global__ void gather_normalize_kernel(const int* __restrict__ cnt,
                                        const int* __restrict__ adj,
                                        const float4* __restrict__ fn,
                                        uint4* __restrict__ vrec) {
  int idx = blockIdx.x * blockDim.x + threadIdx.x;
  if (idx >= kB * kV) return;
  int b = idx / kV;
  int v = idx - b * kV;
  int e = min(cnt[v], kCap);
  float nx = 0.f, ny = 0.f, nz = 0.f, tx = 0.f, ty = 0.f, tzv = 0.f;
  const int* av = adj + v * kCap;
  for (int j = 0; j < e; ++j) {
    int f = av[j];
    size_t k = ((size_t)b * kF + f) * 2;
    float4 a = fn[k];
    float4 c = fn[k + 1];
    nx += a.x;
    ny += a.y;
    nz += a.z;
    tx += a.w;
    ty += c.x;
    tzv += c.y;
  }
  float inv = 1.0f / fmaxf(sqrtf(nx * nx + ny * ny + nz * nz), 1e-6f);
  float invt = 1.0f / fmaxf(sqrtf(tx * tx + ty * ty + tzv * tzv), 1e-6f);
  uint4 r;
  r.x = f2h(nx * inv) | (f2h(ny * inv) << 16);
  r.y = f2h(nz * inv);
  r.z = __float_as_uint(tzv * invt);
  r.w = 0;
  vrec[idx] = r;
}

// Per (b,f): pull 3 packed vertex records (3 x 16B vector gathers) and
// repack into the 32B face record (same layout pixel4 expects).
__global__ void faceattr_kernel(const int* __restrict__ faces,
                                const uint4* __restrict__ vrec,
                                uint4* __restrict__ fattr) {
  int idx = blockIdx.x * blockDim.x + threadIdx.x;
  if (idx >= kB * kF) return;
  int b = idx / kF;
  int f = idx - b * kF;
  int i0 = faces[f * 3 + 0];
  int i1 = faces[f * 3 + 1];
  int i2 = faces[f * 3 + 2];
  const uint4* vb = vrec + (size_t)b * kV;
  uint4 r0 = vb[i0];
  uint4 r1 = vb[i1];
  uint4 r2 = vb[i2];
  uint4 w0, w1;
  w0.x = r0.x;                                      // n0x | n0y
  w0.y = (r0.y & 0xffffu) | (r1.x << 16);           // n0z | n1x
  w0.z = (r1.x >> 16) | ((r1.y & 0xffffu) << 16);   // n1y | n1z
  w0.w = r2.x;                                      // n2x | n2y
  w1.x = r2.y & 0xffffu;                            // n2z
  w1.y = r0.z;                                      // tz0 (f32 bits)
  w1.z = r1.z;                                      // tz1
  w1.w = r2.z;                                      // tz2
  fattr[(size_t)idx * 2 + 0] = w0;
  fattr[(size_t)idx * 2 + 1] = w1;
}

// 4 pixels per thread: 8 independent 16B gathers, scalar light loads,
// non-temporal output stores (keep fattr/bary resident in L2).
__global__ void __launch_bounds__(256) pixel4_kernel(
    const int4* __restrict__ p2f4,
    const float4* __restrict__ bary4,
    const uint4* __restrict__ fattr,
    const float4* __restrict__ ldir4,
    const float4* __restrict__ img4,
    float4* __restrict__ out4) {
  int g = blockIdx.x * blockDim.x + threadIdx.x;
  if (g >= kB * kQ) return;
  int b = g / kQ;
  int q = g - b * kQ;

  int4 f4 = p2f4[g];
  float4 w0 = bary4[(size_t)g * 3 + 0];
  float4 w1 = bary4[(size_t)g * 3 + 1];
  float4 w2 = bary4[(size_t)g * 3 + 2];

  int fi[4] = {f4.x, f4.y, f4.z, f4.w};
  float bw[4][3] = {{w0.x, w0.y, w0.z},
                    {w0.w, w1.x, w1.y},
                    {w1.z, w1.w, w2.x},
                    {w2.y, w2.z, w2.w}};

  // Issue all 8 gathers (independent -> deep MLP).
  uint4 A[4], T[4];
  bool valid[4];
#pragma unroll
  for (int k = 0; k < 4; ++k) {
    bool v = fi[k] < kF;
    valid[k] = v;
    int f = v ? fi[k] : (kF - 1);
    size_t base = ((size_t)b * kF + f) * 2;
    A[k] = fattr[base + 0];
    T[k] = fattr[base + 1];
  }

  size_t ibase = (size_t)b * 3 * kQ + q;
  float4 im0 = img4[ibase + 0 * (size_t)kQ];
  float4 im1 = img4[ibase + 1 * (size_t)kQ];
  float4 im2 = img4[ibase + 2 * (size_t)kQ];
  float im[3][4] = {{im0.x, im0.y, im0.z, im0.w},
                    {im1.x, im1.y, im1.z, im1.w},
                    {im2.x, im2.y, im2.z, im2.w}};

  // Light data: wave-uniform b -> scalar loads.
  int bu = __builtin_amdgcn_readfirstlane(b);
  const float4* lb4 = ldir4 + (size_t)bu * kL * 2;
  float ld[kL][3], lc[kL][3];
#pragma unroll
  for (int l = 0; l < kL; ++l) {
    float4 d = lb4[l * 2 + 0];
    float4 c = lb4[l * 2 + 1];
    ld[l][0] = d.x;
    ld[l][1] = d.y;
    ld[l][2] = d.z;
    lc[l][0] = c.x;
    lc[l][1] = c.y;
    lc[l][2] = c.z;
  }

  float o[3][4];
#pragma unroll
  for (int k = 0; k < 4; ++k) {
    float b0 = bw[k][0], b1 = bw[k][1], b2 = bw[k][2];
    float inv = 1.0f / (b0 + b1 + b2);
    b0 *= inv;
    b1 *= inv;
    b2 *= inv;
    float n0x = h2f(A[k].x), n0y = h2f(A[k].x >> 16);
    float n0z = h2f(A[k].y), n1x = h2f(A[k].y >> 16);
    float n1y = h2f(A[k].z), n1z = h2f(A[k].z >> 16);
    float n2x = h2f(A[k].w), n2y = h2f(A[k].w >> 16);
    float n2z = h2f(T[k].x);
    float tz0 = __uint_as_float(T[k].y);
    float tz1 = __uint_as_float(T[k].z);
    float tz2 = __uint_as_float(T[k].w);

    float tzi = b0 * tz0 + b1 * tz1 + b2 * tz2;
    bool alpha = valid[k] && (tzi < 0.15f);
    float nx = b0 * n0x + b1 * n1x + b2 * n2x;
    float ny = b0 * n0y + b1 * n1y + b2 * n2y;
    float nz = b0 * n0z + b1 * n1z + b2 * n2z;
    float s0 = 0.f, s1 = 0.f, s2 = 0.f;
#pragma unroll
    for (int l = 0; l < kL; ++l) {
      float d = nx * ld[l][0] + ny * ld[l][1] + nz * ld[l][2];
      d = fminf(fmaxf(d, 0.0f), 1.0f);
      s0 += d * lc[l][0];
      s1 += d * lc[l][1];
      s2 += d * lc[l][2];
    }
    const float kk = (180.0f / 255.0f) / (float)kL;
    o[0][k] = alpha ? kk * s0 : im[0][k];
    o[1][k] = alpha ? kk * s1 : im[1][k];
    o[2][k] = alpha ? kk * s2 : im[2][k];
  }

#pragma unroll
  for (int c = 0; c < 3; ++c) {
    nfloat4 v = {o[c][0], o[c][1], o[c][2], o[c][3]};
    __builtin_nontemporal_store(v, (nfloat4*)&out4[ibase + c * (size_t)kQ]);
  }
}

}  // namespace

extern "C" void kernel_launch(void* const* d_in, const int* in_sizes, int n_in,
                              void* d_out, int out_size, void* d_ws, size_t ws_size,
                              hipStream_t stream) {
  const float* vertices = (const float*)d_in[0];
  const float* tvertices = (const float*)d_in[1];
  const float* lights = (const float*)d_in[2];
  const float* images = (const float*)d_in[3];
  const float* bary = (const float*)d_in[4];
  const int* faces = (const int*)d_in[5];
  const int* p2f = (const int*)d_in[6];
  float* out = (float*)d_out;

  // workspace layout (16B-aligned chunks)
  char* ws = (char*)d_ws;
  int* cnt = (int*)ws;                                   // kV ints
  ws += ((size_t)kV * sizeof(int) + 15) & ~15ull;
  int* adj = (int*)ws;                                   // kV*kCap ints
  ws += ((size_t)kV * kCap * sizeof(int) + 15) & ~15ull;
  float4* fn = (float4*)ws;                              // kB*kF*2 float4
  ws += (size_t)kB * kF * 2 * sizeof(float4);
  uint4* vrec = (uint4*)ws;                              // kB*kV uint4
  ws += (size_t)kB * kV * sizeof(uint4);
  float4* ldir4 = (float4*)ws;                           // kB*kL*2 float4
  ws += (size_t)kB * kL * 2 * sizeof(float4);
  uint4* fattr = (uint4*)ws;                             // kB*kF*2 uint4

  {
    init_kernel<<<20, 256, 0, stream>>>(cnt, lights, ldir4);
  }
  {
    int n = kF + kB * kF;
    prep_kernel<<<(n + 255) / 256, 256, 0, stream>>>(vertices, tvertices, faces, cnt,
                                                     adj, fn);
  }
  {
    int n = kB * kV;
    gather_normalize_kernel<<<(n + 255) / 256, 256, 0, stream>>>(cnt, adj, fn, vrec);
  }
  {
    int n = kB * kF;
    faceattr_kernel<<<(n + 255) / 256, 256, 0, stream>>>(faces, vrec, fattr);
  }
  {
    int n = kB * kQ;
    pixel4_kernel<<<(n + 255) / 256, 256, 0, stream>>>((const int4*)p2f, (const float4*)bary,
                                                       fattr, ldir4, (const float4*)images,
                                                       (float4*)out);
  }
}